// Round 16
// baseline (111.807 us; speedup 1.0000x reference)
//
#include <hip/hip_runtime.h>

typedef float float4v __attribute__((ext_vector_type(4)));

__device__ __forceinline__ float sigm(float x) { return 1.0f / (1.0f + __expf(-x)); }

__device__ __forceinline__ float readlane_f(float v, int l) {
    return __int_as_float(__builtin_amdgcn_readlane(__float_as_int(v), l));
}

#define HS_LD 68   // padded leading dim (floats) for staged h in LDS

// ---------------------------------------------------------------------------
// Self-sufficient iteration kernel. ONE block = ONE receiver row (b,i).
// 512 threads = (dim = t>>3 in 0..63) x (c8 = t&7 -> A-columns c8*8..+7).
// Edge features live UNCOMPACTED in per-wave VGPRs (lane L = sender L) and
// are broadcast via v_readlane (bit-exact via int bitcast); inactive senders
// are skipped via the in-register ballot mask (no memory in the skip chain).
// Per-edge LDS traffic: just 2 ds_read_b128 of h[j].
__global__ __launch_bounds__(512) void k_it(
    const float* __restrict__ edges, const float* __restrict__ nodes,
    const float* __restrict__ W_en, const float* __restrict__ b_en,
    const float* __restrict__ W_agg, const float* __restrict__ b_agg,
    const float* __restrict__ W_ih, const float* __restrict__ W_hh,
    const float* __restrict__ b_ih, const float* __restrict__ b_hh,
    const float* __restrict__ h_cur, float* __restrict__ h_next,
    const float* __restrict__ W_r1, const float* __restrict__ b_r1,
    float* __restrict__ Ha, float* __restrict__ Hc, int it0, int emit)
{
    __shared__ float hs[64 * HS_LD];   // h of this batch (17.4 KB)
    __shared__ float xtra[768];        // aggS|g1|h1S|g2i|g2h|hnS

    int t = threadIdx.x;
    int row = blockIdx.x;              // 0..255 = b*64 + i
    int ri = row & 63;
    int b = row >> 6;
    int lane = t & 63;

    // ---- per-wave edge-feature registers: ef[k] = feat k of sender `lane` ----
    float ef[16];
    {
        const float* ep = edges + ((size_t)row * 64 + lane) * 16;
        float4v v0 = *(const float4v*)(ep);
        float4v v1 = *(const float4v*)(ep + 4);
        float4v v2 = *(const float4v*)(ep + 8);
        float4v v3 = *(const float4v*)(ep + 12);
#pragma unroll
        for (int u = 0; u < 4; ++u) {
            ef[u] = v0[u]; ef[4 + u] = v1[u]; ef[8 + u] = v2[u]; ef[12 + u] = v3[u];
        }
    }
    unsigned long long mask = __ballot(ef[0] != 0.f);   // same in every wave

    // ---- stage h[b] into LDS: compute h0 (it0) or load h_cur ----
    if (it0) {
#pragma unroll
        for (int q = 0; q < 8; ++q) {
            int idx = q * 512 + t;             // 4096 = 64 nodes x 64 dims
            int n = idx >> 6, d = idx & 63;    // n wave-uniform -> scalar loads
            const float* np_ = nodes + ((b << 6) + n) * 32;
            float acc = b_en[d];
#pragma unroll
            for (int k = 0; k < 32; ++k)
                acc = fmaf(np_[k], W_en[k * 64 + d], acc);
            hs[n * HS_LD + d] = fmaxf(acc, 0.f);
        }
    } else {
        int n = t >> 3, col = (t & 7) * 8;
        const float* gp = h_cur + ((b << 6) + n) * 64 + col;
        float* lp = hs + n * HS_LD + col;
        *(float4v*)(lp)     = *(const float4v*)(gp);
        *(float4v*)(lp + 4) = *(const float4v*)(gp + 4);
    }

    // ---- resident W fragment: 16 k x 8 cols (32 float4 = 128 VGPR) ----
    int dim = t >> 3, c8 = t & 7;
    float4v w[32];
    {
        const float* wp = W_agg + dim * 64 + c8 * 8;
#pragma unroll
        for (int k = 0; k < 16; ++k) {
            w[2 * k]     = *(const float4v*)(wp + k * 4096);
            w[2 * k + 1] = *(const float4v*)(wp + k * 4096 + 4);
        }
    }
    float4v bias0 = *(const float4v*)(b_agg + dim * 64 + c8 * 8);
    float4v bias1 = *(const float4v*)(b_agg + dim * 64 + c8 * 8 + 4);

    __syncthreads();

    float* aggS = xtra;
    float* g1  = xtra + 64;
    float* h1S = xtra + 256;
    float* g2i = xtra + 320;
    float* g2h = xtra + 512;
    float* hnS = xtra + 704;
    const float* hrow = hs + ri * HS_LD;

    // ---- GRU gate-1 (depends only on hrow): hoisted before the edge loop ----
    if (t < 192) {
        float g = b_ih[t];
        const float* wr = W_ih + t * 64;
#pragma unroll
        for (int k = 0; k < 64; ++k) g = fmaf(hrow[k], wr[k], g);
        g1[t] = g;
    }

    // ---- edge loop: readlane-broadcast features, register mask skip ----
    float rsum = 0.f;
    for (int j = 0; j < 64; ++j) {
        if (!((mask >> j) & 1ull)) continue;   // in-register skip, no loads
        float e[16];
#pragma unroll
        for (int k = 0; k < 16; ++k)
            e[k] = readlane_f(ef[k], j);       // bit-exact broadcast -> SGPR
        float4v a0 = bias0, a1 = bias1;
#pragma unroll
        for (int k = 0; k < 16; ++k) {
#pragma unroll
            for (int u = 0; u < 4; ++u) {
                a0[u] = fmaf(e[k], w[2 * k][u], a0[u]);
                a1[u] = fmaf(e[k], w[2 * k + 1][u], a1[u]);
            }
        }
        const float* hp = hs + j * HS_LD + c8 * 8;
        float4v hv0 = *(const float4v*)(hp);
        float4v hv1 = *(const float4v*)(hp + 4);
#pragma unroll
        for (int u = 0; u < 4; ++u) {
            rsum = fmaf(fmaxf(a0[u], 0.f), hv0[u], rsum);
            rsum = fmaf(fmaxf(a1[u], 0.f), hv1[u], rsum);
        }
    }

    // reduce over the 8 c8-lanes of each dim group
#pragma unroll
    for (int m = 1; m < 8; m <<= 1) rsum += __shfl_xor(rsum, m, 64);
    if (c8 == 0) aggS[dim] = rsum;
    __syncthreads();

    // ---- rest of the fused 2-cell GRU ----
    if (t < 64) {
        float r1 = sigm(g1[t] + b_hh[t]);
        float z1 = sigm(g1[64 + t] + b_hh[64 + t]);
        float nn1 = tanhf(g1[128 + t] + r1 * b_hh[128 + t]);
        h1S[t] = (1.f - z1) * nn1;
    }
    __syncthreads();
    if (t < 192) {
        float gi = b_ih[t];
        float gh = b_hh[t];
        const float* wri = W_ih + t * 64;
        const float* wrh = W_hh + t * 64;
#pragma unroll
        for (int k = 0; k < 64; ++k) {
            gi = fmaf(aggS[k], wri[k], gi);
            gh = fmaf(h1S[k], wrh[k], gh);
        }
        g2i[t] = gi; g2h[t] = gh;
    }
    __syncthreads();
    if (t < 64) {
        float r = sigm(g2i[t] + g2h[t]);
        float z = sigm(g2i[64 + t] + g2h[64 + t]);
        float nn = tanhf(g2i[128 + t] + r * g2h[128 + t]);
        float hn = (1.f - z) * nn + z * h1S[t];
        h_next[row * 64 + t] = hn;
        hnS[t] = hn;
    }
    __syncthreads();
    if (emit && t < 256) {
        // Ha = h @ W1a + b_r1 (W_r1 rows 0..63); Hc = h @ W1c (rows 80..143)
        int m = t >> 7, d = t & 127;
        const float* wbase = W_r1 + (m ? 80 * 128 : 0) + d;
        float acc = m ? 0.f : b_r1[d];
#pragma unroll
        for (int k = 0; k < 64; ++k)
            acc = fmaf(hnS[k], wbase[k * 128], acc);
        if (m == 0) Ha[row * 128 + d] = acc;
        else        Hc[row * 128 + d] = acc;
    }
}

// ---------------------------------------------------------------------------
// Factored readout with inline edge term (proven 32-pair form):
//   a1 = relu(Ha[i] + Hc[j] + e_p @ W1b);  out = relu(a1@W_r2+b2)@W_r3 + b3
__global__ __launch_bounds__(256) void k_read(
    const float* __restrict__ edges,
    const float* __restrict__ Ha, const float* __restrict__ Hc,
    const float* __restrict__ W_r1,
    const float* __restrict__ W_r2, const float* __restrict__ b_r2,
    const float* __restrict__ W_r3, const float* __restrict__ b_r3,
    float* __restrict__ out)
{
    __shared__ float HaS[128];
    __shared__ float eS[32 * 16];    // this unit's 32 edge rows (2 KB)
    __shared__ float A1[32 * 128];   // Hc staged, then a1 in place (16 KB)
    int t = threadIdx.x;
    int unit = blockIdx.x;           // row*2 + qp
    int row = unit >> 1, qp = unit & 1;
    int b = row >> 6;

    const float* src = Hc + (size_t)((b << 6) + qp * 32) * 128;
#pragma unroll
    for (int r = 0; r < 4; ++r) {
        int off = (r * 256 + t) * 4;
        *(float4v*)(A1 + off) = *(const float4v*)(src + off);
    }
    if (t < 32)
        *(float4v*)(HaS + t * 4) = *(const float4v*)(Ha + (size_t)row * 128 + t * 4);
    if (t < 128)   // edges of pairs qp*32..+32: contiguous 512 floats
        *(float4v*)(eS + t * 4) =
            *(const float4v*)(edges + ((size_t)row * 64 + qp * 32) * 16 + t * 4);
    __syncthreads();

    int td = t & 31, pg = t >> 5;    // dims td*4..+3 ; pairs pg*4..+3

    // layer-1 edge term: ew[pi][u] = sum_k e[p][k] * W1b[k][td*4+u]
    float4v ew0 = {0,0,0,0}, ew1 = ew0, ew2 = ew0, ew3 = ew0;
#pragma unroll
    for (int k = 0; k < 16; ++k) {
        float4v wk = *(const float4v*)(W_r1 + (64 + k) * 128 + td * 4);
        float e0 = eS[(pg * 4 + 0) * 16 + k];
        float e1 = eS[(pg * 4 + 1) * 16 + k];
        float e2 = eS[(pg * 4 + 2) * 16 + k];
        float e3 = eS[(pg * 4 + 3) * 16 + k];
#pragma unroll
        for (int u = 0; u < 4; ++u) {
            ew0[u] = fmaf(e0, wk[u], ew0[u]);
            ew1[u] = fmaf(e1, wk[u], ew1[u]);
            ew2[u] = fmaf(e2, wk[u], ew2[u]);
            ew3[u] = fmaf(e3, wk[u], ew3[u]);
        }
    }
    float4v ha = *(const float4v*)(HaS + td * 4);
#pragma unroll
    for (int pi = 0; pi < 4; ++pi) {
        float4v ew = (pi == 0) ? ew0 : (pi == 1) ? ew1 : (pi == 2) ? ew2 : ew3;
        float* slot = A1 + (pg * 4 + pi) * 128 + td * 4;
        float4v hc = *(const float4v*)slot;
        float4v a;
#pragma unroll
        for (int u = 0; u < 4; ++u) a[u] = fmaxf(hc[u] + ha[u] + ew[u], 0.f);
        *(float4v*)slot = a;
    }
    __syncthreads();

    // layer 2
    float4v bb2 = *(const float4v*)(b_r2 + td * 4);
    float4v acc0 = bb2, acc1 = bb2, acc2 = bb2, acc3 = bb2;
    for (int k4 = 0; k4 < 32; ++k4) {
        float4v wA = *(const float4v*)(W_r2 + (k4 * 4 + 0) * 128 + td * 4);
        float4v wB = *(const float4v*)(W_r2 + (k4 * 4 + 1) * 128 + td * 4);
        float4v wC = *(const float4v*)(W_r2 + (k4 * 4 + 2) * 128 + td * 4);
        float4v wD = *(const float4v*)(W_r2 + (k4 * 4 + 3) * 128 + td * 4);
        float4v a0 = *(const float4v*)(A1 + (pg * 4 + 0) * 128 + k4 * 4);
        float4v a1 = *(const float4v*)(A1 + (pg * 4 + 1) * 128 + k4 * 4);
        float4v a2 = *(const float4v*)(A1 + (pg * 4 + 2) * 128 + k4 * 4);
        float4v a3 = *(const float4v*)(A1 + (pg * 4 + 3) * 128 + k4 * 4);
#pragma unroll
        for (int u = 0; u < 4; ++u) {
            acc0[u] = fmaf(a0[0], wA[u], acc0[u]);
            acc0[u] = fmaf(a0[1], wB[u], acc0[u]);
            acc0[u] = fmaf(a0[2], wC[u], acc0[u]);
            acc0[u] = fmaf(a0[3], wD[u], acc0[u]);
            acc1[u] = fmaf(a1[0], wA[u], acc1[u]);
            acc1[u] = fmaf(a1[1], wB[u], acc1[u]);
            acc1[u] = fmaf(a1[2], wC[u], acc1[u]);
            acc1[u] = fmaf(a1[3], wD[u], acc1[u]);
            acc2[u] = fmaf(a2[0], wA[u], acc2[u]);
            acc2[u] = fmaf(a2[1], wB[u], acc2[u]);
            acc2[u] = fmaf(a2[2], wC[u], acc2[u]);
            acc2[u] = fmaf(a2[3], wD[u], acc2[u]);
            acc3[u] = fmaf(a3[0], wA[u], acc3[u]);
            acc3[u] = fmaf(a3[1], wB[u], acc3[u]);
            acc3[u] = fmaf(a3[2], wC[u], acc3[u]);
            acc3[u] = fmaf(a3[3], wD[u], acc3[u]);
        }
    }

    // layer 3
    float4v w3v = *(const float4v*)(W_r3 + td * 4);
    float b3 = b_r3[0];
    float p0 = fmaxf(acc0[0], 0.f) * w3v[0] + fmaxf(acc0[1], 0.f) * w3v[1]
             + fmaxf(acc0[2], 0.f) * w3v[2] + fmaxf(acc0[3], 0.f) * w3v[3];
    float p1 = fmaxf(acc1[0], 0.f) * w3v[0] + fmaxf(acc1[1], 0.f) * w3v[1]
             + fmaxf(acc1[2], 0.f) * w3v[2] + fmaxf(acc1[3], 0.f) * w3v[3];
    float p2 = fmaxf(acc2[0], 0.f) * w3v[0] + fmaxf(acc2[1], 0.f) * w3v[1]
             + fmaxf(acc2[2], 0.f) * w3v[2] + fmaxf(acc2[3], 0.f) * w3v[3];
    float p3 = fmaxf(acc3[0], 0.f) * w3v[0] + fmaxf(acc3[1], 0.f) * w3v[1]
             + fmaxf(acc3[2], 0.f) * w3v[2] + fmaxf(acc3[3], 0.f) * w3v[3];
#pragma unroll
    for (int m = 1; m < 32; m <<= 1) {
        p0 += __shfl_xor(p0, m, 64);
        p1 += __shfl_xor(p1, m, 64);
        p2 += __shfl_xor(p2, m, 64);
        p3 += __shfl_xor(p3, m, 64);
    }
    if (td == 0) {
        int obase = row * 64 + qp * 32 + pg * 4;
        out[obase + 0] = p0 + b3;
        out[obase + 1] = p1 + b3;
        out[obase + 2] = p2 + b3;
        out[obase + 3] = p3 + b3;
    }
}

// ---------------------------------------------------------------------------
extern "C" void kernel_launch(void* const* d_in, const int* in_sizes, int n_in,
                              void* d_out, int out_size, void* d_ws, size_t ws_size,
                              hipStream_t stream)
{
    const float* edges = (const float*)d_in[0];
    const float* nodes = (const float*)d_in[1];
    // d_in[2] adjacency: unused
    const float* W_en  = (const float*)d_in[3];
    const float* b_en  = (const float*)d_in[4];
    const float* W_agg = (const float*)d_in[5];
    const float* b_agg = (const float*)d_in[6];
    const float* W_ih  = (const float*)d_in[7];
    const float* W_hh  = (const float*)d_in[8];
    const float* b_ih  = (const float*)d_in[9];
    const float* b_hh  = (const float*)d_in[10];
    const float* W_r1  = (const float*)d_in[11];
    const float* b_r1  = (const float*)d_in[12];
    const float* W_r2  = (const float*)d_in[13];
    const float* b_r2  = (const float*)d_in[14];
    const float* W_r3  = (const float*)d_in[15];
    const float* b_r3  = (const float*)d_in[16];

    // workspace (~400 KB, fully rewritten every call)
    float* hA = (float*)d_ws;          // 16384
    float* hB = hA + 16384;            // 16384
    float* Ha = hB + 16384;            // 256*128
    float* Hc = Ha + 256 * 128;        // 256*128
    float* out = (float*)d_out;

    k_it<<<256, 512, 0, stream>>>(edges, nodes, W_en, b_en, W_agg, b_agg,
                                  W_ih, W_hh, b_ih, b_hh, hA, hA,
                                  W_r1, b_r1, Ha, Hc, 1, 0);
    k_it<<<256, 512, 0, stream>>>(edges, nodes, W_en, b_en, W_agg, b_agg,
                                  W_ih, W_hh, b_ih, b_hh, hA, hB,
                                  W_r1, b_r1, Ha, Hc, 0, 0);
    k_it<<<256, 512, 0, stream>>>(edges, nodes, W_en, b_en, W_agg, b_agg,
                                  W_ih, W_hh, b_ih, b_hh, hB, hA,
                                  W_r1, b_r1, Ha, Hc, 0, 1);
    k_read<<<512, 256, 0, stream>>>(edges, Ha, Hc, W_r1, W_r2, b_r2,
                                    W_r3, b_r3, out);
}

// Round 17
// 78.301 us; speedup vs baseline: 1.4279x; 1.4279x over previous
//
#include <hip/hip_runtime.h>

typedef float float4v __attribute__((ext_vector_type(4)));

__device__ __forceinline__ float sigm(float x) { return 1.0f / (1.0f + __expf(-x)); }

#define HS_LD 68   // padded leading dim (floats) for staged h in LDS

// ---------------------------------------------------------------------------
// Self-sufficient iteration kernel. ONE block = ONE receiver row (b,i).
// 512 threads = (dim = t>>3 in 0..63) x (c8 = t&7 -> A-columns c8*8..+7).
// W fragment = 16k x 8 cols = 128 VGPR -> per edge: 4 broadcast eL reads,
// 1 jn read, 2 hs reads, 136 VALU  => LDS-issue ~ VALU (balanced).
__global__ __launch_bounds__(512) void k_it(
    const float* __restrict__ edges, const float* __restrict__ nodes,
    const float* __restrict__ W_en, const float* __restrict__ b_en,
    const float* __restrict__ W_agg, const float* __restrict__ b_agg,
    const float* __restrict__ W_ih, const float* __restrict__ W_hh,
    const float* __restrict__ b_ih, const float* __restrict__ b_hh,
    const float* __restrict__ h_cur, float* __restrict__ h_next,
    const float* __restrict__ W_r1, const float* __restrict__ b_r1,
    float* __restrict__ Ha, float* __restrict__ Hc, int it0, int emit)
{
    __shared__ float hs[64 * HS_LD];   // h of this batch (17.4 KB)
    __shared__ float eL[64 * 16];      // packed active-edge features (4 KB)
    __shared__ int   jn[64];           // slot -> sender j
    __shared__ int   nES;
    __shared__ float xtra[768];        // aggS|g1|h1S|g2i|g2h|hnS

    int t = threadIdx.x;
    int row = blockIdx.x;              // 0..255 = b*64 + i
    int ri = row & 63;
    int b = row >> 6;

    // ---- stage h[b] into LDS: compute h0 (it0) or load h_cur ----
    if (it0) {
#pragma unroll
        for (int q = 0; q < 8; ++q) {
            int idx = q * 512 + t;             // 4096 = 64 nodes x 64 dims
            int n = idx >> 6, d = idx & 63;    // n wave-uniform -> scalar loads
            const float* np_ = nodes + ((b << 6) + n) * 32;
            float acc = b_en[d];
#pragma unroll
            for (int k = 0; k < 32; ++k)
                acc = fmaf(np_[k], W_en[k * 64 + d], acc);
            hs[n * HS_LD + d] = fmaxf(acc, 0.f);
        }
    } else {
        int n = t >> 3, col = (t & 7) * 8;
        const float* gp = h_cur + ((b << 6) + n) * 64 + col;
        float* lp = hs + n * HS_LD + col;
        *(float4v*)(lp)     = *(const float4v*)(gp);
        *(float4v*)(lp + 4) = *(const float4v*)(gp + 4);
    }

    // ---- pack own row's active edges (wave 0 only; ascending j) ----
    if (t < 64) {
        const float* ep = edges + ((size_t)row * 64 + t) * 16;
        float f0 = ep[0];
        unsigned long long m = __ballot(f0 != 0.f);
        if (t == 0) nES = __popcll(m);
        if (f0 != 0.f) {
            int pos = __popcll(m & ((1ull << t) - 1ull));
            jn[pos] = t;
            float* dst = eL + pos * 16;
#pragma unroll
            for (int u = 0; u < 4; ++u)
                *(float4v*)(dst + u * 4) = *(const float4v*)(ep + u * 4);
        }
    }

    // ---- resident W fragment: 16 k x 8 cols (32 float4 = 128 VGPR) ----
    int dim = t >> 3, c8 = t & 7;
    float4v w[32];
    {
        const float* wp = W_agg + dim * 64 + c8 * 8;
#pragma unroll
        for (int k = 0; k < 16; ++k) {
            w[2 * k]     = *(const float4v*)(wp + k * 4096);
            w[2 * k + 1] = *(const float4v*)(wp + k * 4096 + 4);
        }
    }
    float4v bias0 = *(const float4v*)(b_agg + dim * 64 + c8 * 8);
    float4v bias1 = *(const float4v*)(b_agg + dim * 64 + c8 * 8 + 4);

    __syncthreads();
    int nE = nES;

    float* aggS = xtra;
    float* g1  = xtra + 64;
    float* h1S = xtra + 256;
    float* g2i = xtra + 320;
    float* g2h = xtra + 512;
    float* hnS = xtra + 704;
    const float* hrow = hs + ri * HS_LD;

    // ---- GRU gate-1 (depends only on hrow): hoisted before the edge loop ----
    if (t < 192) {
        float g = b_ih[t];
        const float* wr = W_ih + t * 64;
#pragma unroll
        for (int k = 0; k < 64; ++k) g = fmaf(hrow[k], wr[k], g);
        g1[t] = g;
    }

    // ---- edge loop: packed LDS stream, computable addresses ----
    float rsum = 0.f;
    for (int s = 0; s < nE; ++s) {
        const float* eP = eL + s * 16;
        float4v e0 = *(const float4v*)(eP);
        float4v e1 = *(const float4v*)(eP + 4);
        float4v e2 = *(const float4v*)(eP + 8);
        float4v e3 = *(const float4v*)(eP + 12);
        int ej = jn[s];
        float4v a0 = bias0, a1 = bias1;
#pragma unroll
        for (int k = 0; k < 4; ++k) {
#pragma unroll
            for (int u = 0; u < 4; ++u) {
                a0[u] = fmaf(e0[k], w[2 * k][u], a0[u]);
                a1[u] = fmaf(e0[k], w[2 * k + 1][u], a1[u]);
            }
        }
#pragma unroll
        for (int k = 0; k < 4; ++k) {
#pragma unroll
            for (int u = 0; u < 4; ++u) {
                a0[u] = fmaf(e1[k], w[2 * (4 + k)][u], a0[u]);
                a1[u] = fmaf(e1[k], w[2 * (4 + k) + 1][u], a1[u]);
            }
        }
#pragma unroll
        for (int k = 0; k < 4; ++k) {
#pragma unroll
            for (int u = 0; u < 4; ++u) {
                a0[u] = fmaf(e2[k], w[2 * (8 + k)][u], a0[u]);
                a1[u] = fmaf(e2[k], w[2 * (8 + k) + 1][u], a1[u]);
            }
        }
#pragma unroll
        for (int k = 0; k < 4; ++k) {
#pragma unroll
            for (int u = 0; u < 4; ++u) {
                a0[u] = fmaf(e3[k], w[2 * (12 + k)][u], a0[u]);
                a1[u] = fmaf(e3[k], w[2 * (12 + k) + 1][u], a1[u]);
            }
        }
        const float* hp = hs + ej * HS_LD + c8 * 8;
        float4v hv0 = *(const float4v*)(hp);
        float4v hv1 = *(const float4v*)(hp + 4);
#pragma unroll
        for (int u = 0; u < 4; ++u) {
            rsum = fmaf(fmaxf(a0[u], 0.f), hv0[u], rsum);
            rsum = fmaf(fmaxf(a1[u], 0.f), hv1[u], rsum);
        }
    }

    // reduce over the 8 c8-lanes of each dim group
#pragma unroll
    for (int m = 1; m < 8; m <<= 1) rsum += __shfl_xor(rsum, m, 64);
    if (c8 == 0) aggS[dim] = rsum;
    __syncthreads();

    // ---- rest of the fused 2-cell GRU ----
    if (t < 64) {
        float r1 = sigm(g1[t] + b_hh[t]);
        float z1 = sigm(g1[64 + t] + b_hh[64 + t]);
        float nn1 = tanhf(g1[128 + t] + r1 * b_hh[128 + t]);
        h1S[t] = (1.f - z1) * nn1;
    }
    __syncthreads();
    if (t < 192) {
        float gi = b_ih[t];
        float gh = b_hh[t];
        const float* wri = W_ih + t * 64;
        const float* wrh = W_hh + t * 64;
#pragma unroll
        for (int k = 0; k < 64; ++k) {
            gi = fmaf(aggS[k], wri[k], gi);
            gh = fmaf(h1S[k], wrh[k], gh);
        }
        g2i[t] = gi; g2h[t] = gh;
    }
    __syncthreads();
    if (t < 64) {
        float r = sigm(g2i[t] + g2h[t]);
        float z = sigm(g2i[64 + t] + g2h[64 + t]);
        float nn = tanhf(g2i[128 + t] + r * g2h[128 + t]);
        float hn = (1.f - z) * nn + z * h1S[t];
        h_next[row * 64 + t] = hn;
        hnS[t] = hn;
    }
    __syncthreads();
    if (emit && t < 256) {
        // Ha = h @ W1a + b_r1 (W_r1 rows 0..63); Hc = h @ W1c (rows 80..143)
        int m = t >> 7, d = t & 127;
        const float* wbase = W_r1 + (m ? 80 * 128 : 0) + d;
        float acc = m ? 0.f : b_r1[d];
#pragma unroll
        for (int k = 0; k < 64; ++k)
            acc = fmaf(hnS[k], wbase[k * 128], acc);
        if (m == 0) Ha[row * 128 + d] = acc;
        else        Hc[row * 128 + d] = acc;
    }
}

// ---------------------------------------------------------------------------
// Factored readout with inline edge term (proven 32-pair form):
//   a1 = relu(Ha[i] + Hc[j] + e_p @ W1b);  out = relu(a1@W_r2+b2)@W_r3 + b3
__global__ __launch_bounds__(256) void k_read(
    const float* __restrict__ edges,
    const float* __restrict__ Ha, const float* __restrict__ Hc,
    const float* __restrict__ W_r1,
    const float* __restrict__ W_r2, const float* __restrict__ b_r2,
    const float* __restrict__ W_r3, const float* __restrict__ b_r3,
    float* __restrict__ out)
{
    __shared__ float HaS[128];
    __shared__ float eS[32 * 16];    // this unit's 32 edge rows (2 KB)
    __shared__ float A1[32 * 128];   // Hc staged, then a1 in place (16 KB)
    int t = threadIdx.x;
    int unit = blockIdx.x;           // row*2 + qp
    int row = unit >> 1, qp = unit & 1;
    int b = row >> 6;

    const float* src = Hc + (size_t)((b << 6) + qp * 32) * 128;
#pragma unroll
    for (int r = 0; r < 4; ++r) {
        int off = (r * 256 + t) * 4;
        *(float4v*)(A1 + off) = *(const float4v*)(src + off);
    }
    if (t < 32)
        *(float4v*)(HaS + t * 4) = *(const float4v*)(Ha + (size_t)row * 128 + t * 4);
    if (t < 128)   // edges of pairs qp*32..+32: contiguous 512 floats
        *(float4v*)(eS + t * 4) =
            *(const float4v*)(edges + ((size_t)row * 64 + qp * 32) * 16 + t * 4);
    __syncthreads();

    int td = t & 31, pg = t >> 5;    // dims td*4..+3 ; pairs pg*4..+3

    // layer-1 edge term: ew[pi][u] = sum_k e[p][k] * W1b[k][td*4+u]
    float4v ew0 = {0,0,0,0}, ew1 = ew0, ew2 = ew0, ew3 = ew0;
#pragma unroll
    for (int k = 0; k < 16; ++k) {
        float4v wk = *(const float4v*)(W_r1 + (64 + k) * 128 + td * 4);
        float e0 = eS[(pg * 4 + 0) * 16 + k];
        float e1 = eS[(pg * 4 + 1) * 16 + k];
        float e2 = eS[(pg * 4 + 2) * 16 + k];
        float e3 = eS[(pg * 4 + 3) * 16 + k];
#pragma unroll
        for (int u = 0; u < 4; ++u) {
            ew0[u] = fmaf(e0, wk[u], ew0[u]);
            ew1[u] = fmaf(e1, wk[u], ew1[u]);
            ew2[u] = fmaf(e2, wk[u], ew2[u]);
            ew3[u] = fmaf(e3, wk[u], ew3[u]);
        }
    }
    float4v ha = *(const float4v*)(HaS + td * 4);
#pragma unroll
    for (int pi = 0; pi < 4; ++pi) {
        float4v ew = (pi == 0) ? ew0 : (pi == 1) ? ew1 : (pi == 2) ? ew2 : ew3;
        float* slot = A1 + (pg * 4 + pi) * 128 + td * 4;
        float4v hc = *(const float4v*)slot;
        float4v a;
#pragma unroll
        for (int u = 0; u < 4; ++u) a[u] = fmaxf(hc[u] + ha[u] + ew[u], 0.f);
        *(float4v*)slot = a;
    }
    __syncthreads();

    // layer 2
    float4v bb2 = *(const float4v*)(b_r2 + td * 4);
    float4v acc0 = bb2, acc1 = bb2, acc2 = bb2, acc3 = bb2;
    for (int k4 = 0; k4 < 32; ++k4) {
        float4v wA = *(const float4v*)(W_r2 + (k4 * 4 + 0) * 128 + td * 4);
        float4v wB = *(const float4v*)(W_r2 + (k4 * 4 + 1) * 128 + td * 4);
        float4v wC = *(const float4v*)(W_r2 + (k4 * 4 + 2) * 128 + td * 4);
        float4v wD = *(const float4v*)(W_r2 + (k4 * 4 + 3) * 128 + td * 4);
        float4v a0 = *(const float4v*)(A1 + (pg * 4 + 0) * 128 + k4 * 4);
        float4v a1 = *(const float4v*)(A1 + (pg * 4 + 1) * 128 + k4 * 4);
        float4v a2 = *(const float4v*)(A1 + (pg * 4 + 2) * 128 + k4 * 4);
        float4v a3 = *(const float4v*)(A1 + (pg * 4 + 3) * 128 + k4 * 4);
#pragma unroll
        for (int u = 0; u < 4; ++u) {
            acc0[u] = fmaf(a0[0], wA[u], acc0[u]);
            acc0[u] = fmaf(a0[1], wB[u], acc0[u]);
            acc0[u] = fmaf(a0[2], wC[u], acc0[u]);
            acc0[u] = fmaf(a0[3], wD[u], acc0[u]);
            acc1[u] = fmaf(a1[0], wA[u], acc1[u]);
            acc1[u] = fmaf(a1[1], wB[u], acc1[u]);
            acc1[u] = fmaf(a1[2], wC[u], acc1[u]);
            acc1[u] = fmaf(a1[3], wD[u], acc1[u]);
            acc2[u] = fmaf(a2[0], wA[u], acc2[u]);
            acc2[u] = fmaf(a2[1], wB[u], acc2[u]);
            acc2[u] = fmaf(a2[2], wC[u], acc2[u]);
            acc2[u] = fmaf(a2[3], wD[u], acc2[u]);
            acc3[u] = fmaf(a3[0], wA[u], acc3[u]);
            acc3[u] = fmaf(a3[1], wB[u], acc3[u]);
            acc3[u] = fmaf(a3[2], wC[u], acc3[u]);
            acc3[u] = fmaf(a3[3], wD[u], acc3[u]);
        }
    }

    // layer 3
    float4v w3v = *(const float4v*)(W_r3 + td * 4);
    float b3 = b_r3[0];
    float p0 = fmaxf(acc0[0], 0.f) * w3v[0] + fmaxf(acc0[1], 0.f) * w3v[1]
             + fmaxf(acc0[2], 0.f) * w3v[2] + fmaxf(acc0[3], 0.f) * w3v[3];
    float p1 = fmaxf(acc1[0], 0.f) * w3v[0] + fmaxf(acc1[1], 0.f) * w3v[1]
             + fmaxf(acc1[2], 0.f) * w3v[2] + fmaxf(acc1[3], 0.f) * w3v[3];
    float p2 = fmaxf(acc2[0], 0.f) * w3v[0] + fmaxf(acc2[1], 0.f) * w3v[1]
             + fmaxf(acc2[2], 0.f) * w3v[2] + fmaxf(acc2[3], 0.f) * w3v[3];
    float p3 = fmaxf(acc3[0], 0.f) * w3v[0] + fmaxf(acc3[1], 0.f) * w3v[1]
             + fmaxf(acc3[2], 0.f) * w3v[2] + fmaxf(acc3[3], 0.f) * w3v[3];
#pragma unroll
    for (int m = 1; m < 32; m <<= 1) {
        p0 += __shfl_xor(p0, m, 64);
        p1 += __shfl_xor(p1, m, 64);
        p2 += __shfl_xor(p2, m, 64);
        p3 += __shfl_xor(p3, m, 64);
    }
    if (td == 0) {
        int obase = row * 64 + qp * 32 + pg * 4;
        out[obase + 0] = p0 + b3;
        out[obase + 1] = p1 + b3;
        out[obase + 2] = p2 + b3;
        out[obase + 3] = p3 + b3;
    }
}

// ---------------------------------------------------------------------------
extern "C" void kernel_launch(void* const* d_in, const int* in_sizes, int n_in,
                              void* d_out, int out_size, void* d_ws, size_t ws_size,
                              hipStream_t stream)
{
    const float* edges = (const float*)d_in[0];
    const float* nodes = (const float*)d_in[1];
    // d_in[2] adjacency: unused
    const float* W_en  = (const float*)d_in[3];
    const float* b_en  = (const float*)d_in[4];
    const float* W_agg = (const float*)d_in[5];
    const float* b_agg = (const float*)d_in[6];
    const float* W_ih  = (const float*)d_in[7];
    const float* W_hh  = (const float*)d_in[8];
    const float* b_ih  = (const float*)d_in[9];
    const float* b_hh  = (const float*)d_in[10];
    const float* W_r1  = (const float*)d_in[11];
    const float* b_r1  = (const float*)d_in[12];
    const float* W_r2  = (const float*)d_in[13];
    const float* b_r2  = (const float*)d_in[14];
    const float* W_r3  = (const float*)d_in[15];
    const float* b_r3  = (const float*)d_in[16];

    // workspace (~400 KB, fully rewritten every call)
    float* hA = (float*)d_ws;          // 16384
    float* hB = hA + 16384;            // 16384
    float* Ha = hB + 16384;            // 256*128
    float* Hc = Ha + 256 * 128;        // 256*128
    float* out = (float*)d_out;

    k_it<<<256, 512, 0, stream>>>(edges, nodes, W_en, b_en, W_agg, b_agg,
                                  W_ih, W_hh, b_ih, b_hh, hA, hA,
                                  W_r1, b_r1, Ha, Hc, 1, 0);
    k_it<<<256, 512, 0, stream>>>(edges, nodes, W_en, b_en, W_agg, b_agg,
                                  W_ih, W_hh, b_ih, b_hh, hA, hB,
                                  W_r1, b_r1, Ha, Hc, 0, 0);
    k_it<<<256, 512, 0, stream>>>(edges, nodes, W_en, b_en, W_agg, b_agg,
                                  W_ih, W_hh, b_ih, b_hh, hB, hA,
                                  W_r1, b_r1, Ha, Hc, 0, 1);
    k_read<<<512, 256, 0, stream>>>(edges, Ha, Hc, W_r1, W_r2, b_r2,
                                    W_r3, b_r3, out);
}